// Round 9
// baseline (98.077 us; speedup 1.0000x reference)
//
#include <hip/hip_runtime.h>
#include <math.h>

#define BB   4
#define NN   4096
#define DD   128
#define NCLS 5
#define SS   800      // (N - NQ) / NCLS
#define KK   400      // int(0.5 * S)
#define NQ   96
#define MM   (NCLS*KK + NQ)   // 2096
#define NSUP (NCLS*SS)        // 4000

typedef float f4 __attribute__((ext_vector_type(4)));

// ---------------- scores: f64 dot, exact f32 sigmoid (R2/R3-verified, verbatim) ----------------
__global__ void score_kernel(const float* __restrict__ X, const float* __restrict__ W,
                             const float* __restrict__ bias,
                             float* __restrict__ scoreF) {
    int row  = blockIdx.x * 4 + (threadIdx.x >> 6);   // 4 waves / block
    int lane = threadIdx.x & 63;
    if (row >= BB * NN) return;
    const float* x = X + (size_t)row * DD;
    double acc = (double)x[lane]      * (double)W[lane]
               + (double)x[lane + 64] * (double)W[lane + 64];
    #pragma unroll
    for (int off = 32; off > 0; off >>= 1) acc += __shfl_down(acc, off);
    if (lane == 0) {
        float z32 = (float)acc;
        float u   = (z32 + bias[0]) / 100.0f;
        float e   = (float)exp(-(double)u);
        float t   = 1.0f + e;
        float s   = 1.0f / t;
        scoreF[row] = s;
    }
}

// ---------------- top-400 per (b,class): register bitonic (R3-verified, verbatim) ----------------
__global__ void __launch_bounds__(1024)
topk_kernel(const float* __restrict__ scoreF, int* __restrict__ gidx, float* __restrict__ gvals) {
    __shared__ unsigned long long buf[2][1024];
    const int b = blockIdx.x / NCLS;
    const int c = blockIdx.x % NCLS;
    const int t = threadIdx.x;

    if (c == 0 && t >= 512 && t < 512 + NQ) {
        int q  = t - 512;
        int gi = NSUP + q;
        int m  = NCLS * KK + q;
        gidx [b * MM + m] = gi;
        gvals[b * MM + m] = scoreF[(size_t)b * NN + gi];
    }

    const float* sc = scoreF + (size_t)b * NN + c * SS;
    unsigned long long v = 0ull;    // pad sinks
    if (t < SS)
        v = ((unsigned long long)__float_as_uint(sc[t]) << 32) | (unsigned int)(1023 - t);

    int p = 0;
    for (int k = 2; k <= 1024; k <<= 1) {
        for (int j = k >> 1; j > 0; j >>= 1) {
            unsigned long long o;
            if (j >= 64) {
                buf[p][t] = v;
                __syncthreads();
                o = buf[p][t ^ j];
                p ^= 1;   // next reuse of this buffer is 2 stages (1 barrier) away
            } else {
                unsigned int lo = __shfl_xor((unsigned int)(v & 0xFFFFFFFFu), j);
                unsigned int hi = __shfl_xor((unsigned int)(v >> 32), j);
                o = ((unsigned long long)hi << 32) | lo;
            }
            bool keepMax = (((t & k) == 0) == ((t & j) == 0));
            v = keepMax ? (v > o ? v : o) : (v < o ? v : o);
        }
    }

    if (t < KK) {
        int li = 1023 - (int)(v & 0xFFFFFFFFull);
        gidx [b * MM + c * KK + t] = c * SS + li;
        gvals[b * MM + c * KK + t] = __uint_as_float((unsigned int)(v >> 32));
    }
}

// ---------------- fused new_A + new_X + idx (R8 verbatim; launched TWICE this round
// as a timing bisect — idempotent, deterministic) ----------------
__global__ void __launch_bounds__(256)
newxa_kernel(const float* __restrict__ A, const float* __restrict__ X,
             const int* __restrict__ gidx, const float* __restrict__ gvals,
             float* __restrict__ outA, float* __restrict__ outX, float* __restrict__ outIdx) {
    __shared__ int   cidx[MM];
    __shared__ float rowA[NN];
    const int bm = blockIdx.x;            // b*MM + i
    const int b  = bm / MM;
    const int ri = gidx[bm];              // broadcast scalar load (gidx L2-hot)

    {
        const float* arow = A + ((size_t)b * NN + ri) * NN;
        const int wv = threadIdx.x >> 6, ln = threadIdx.x & 63;
        #pragma unroll
        for (int sgm = 0; sgm < 4; ++sgm) {
            int base = (wv * 4 + sgm) * 256;               // float offset, wave-uniform
            const float* gsrc = arow + base + ln * 4;      // per-lane global addr
            float*       ldst = rowA + base;               // wave-uniform LDS base
            __builtin_amdgcn_global_load_lds(
                (__attribute__((address_space(1))) void*)(const_cast<float*>(gsrc)),
                (__attribute__((address_space(3))) void*)(ldst),
                16, 0, 0);
        }
    }

    const int* gb = gidx + b * MM;
    for (int j = threadIdx.x; j < MM; j += 256) cidx[j] = gb[j];

    if (threadIdx.x < DD) {
        float vscale = gvals[bm];
        outX[(size_t)bm * DD + threadIdx.x] =
            X[((size_t)b * NN + ri) * DD + threadIdx.x] * vscale;
        if (threadIdx.x == 0) outIdx[bm] = (float)ri;
    }
    __syncthreads();   // drains vmcnt (global_load_lds) + lgkmcnt (cidx writes)

    float* orow = outA + (size_t)bm * MM;
    for (int jj = threadIdx.x * 4; jj < MM; jj += 1024) {
        f4 vv;
        vv.x = rowA[cidx[jj]];
        vv.y = rowA[cidx[jj + 1]];
        vv.z = rowA[cidx[jj + 2]];
        vv.w = rowA[cidx[jj + 3]];
        *(f4*)(orow + jj) = vv;
    }
}

extern "C" void kernel_launch(void* const* d_in, const int* in_sizes, int n_in,
                              void* d_out, int out_size, void* d_ws, size_t ws_size,
                              hipStream_t stream) {
    const float* A  = (const float*)d_in[0];
    const float* X  = (const float*)d_in[1];
    const float* W  = (const float*)d_in[2];
    const float* bi = (const float*)d_in[3];

    float* outA   = (float*)d_out;                         // B*M*M
    float* outX   = outA + (size_t)BB * MM * MM;           // B*M*D
    float* outIdx = outX + (size_t)BB * MM * DD;           // B*M

    char* ws = (char*)d_ws;
    float* scoreF = (float*)ws;                                 // B*N*4 = 65536
    int*   gidx   = (int*)  (ws + 65536);                       // B*M*4 = 33536
    float* gvals  = (float*)(ws + 65536 + 33536);               // B*M*4 = 33536

    score_kernel<<<(BB * NN) / 4, 256, 0, stream>>>(X, W, bi, scoreF);
    topk_kernel<<<BB * NCLS, 1024, 0, stream>>>(scoreF, gidx, gvals);
    // TIMING BISECT: newxa launched twice (idempotent). dur - dur_R8 = t_newxa + gap.
    newxa_kernel<<<BB * MM, 256, 0, stream>>>(A, X, gidx, gvals, outA, outX, outIdx);
    newxa_kernel<<<BB * MM, 256, 0, stream>>>(A, X, gidx, gvals, outA, outX, outIdx);
}

// Round 10
// 54.198 us; speedup vs baseline: 1.8096x; 1.8096x over previous
//
#include <hip/hip_runtime.h>
#include <math.h>

#define BB   4
#define NN   4096
#define DD   128
#define NCLS 5
#define SS   800      // (N - NQ) / NCLS
#define KK   400      // int(0.5 * S)
#define NQ   96
#define MM   (NCLS*KK + NQ)   // 2096
#define NSUP (NCLS*SS)        // 4000

typedef float f4 __attribute__((ext_vector_type(4)));
typedef int   i4 __attribute__((ext_vector_type(4)));

// ---------------- scores: f64 dot, exact f32 sigmoid (R2/R3-verified, verbatim) ----------------
__global__ void score_kernel(const float* __restrict__ X, const float* __restrict__ W,
                             const float* __restrict__ bias,
                             float* __restrict__ scoreF) {
    int row  = blockIdx.x * 4 + (threadIdx.x >> 6);   // 4 waves / block
    int lane = threadIdx.x & 63;
    if (row >= BB * NN) return;
    const float* x = X + (size_t)row * DD;
    double acc = (double)x[lane]      * (double)W[lane]
               + (double)x[lane + 64] * (double)W[lane + 64];
    #pragma unroll
    for (int off = 32; off > 0; off >>= 1) acc += __shfl_down(acc, off);
    if (lane == 0) {
        float z32 = (float)acc;
        float u   = (z32 + bias[0]) / 100.0f;
        float e   = (float)exp(-(double)u);
        float t   = 1.0f + e;
        float s   = 1.0f / t;
        scoreF[row] = s;
    }
}

// ---------------- top-400 per (b,class): register bitonic (R3-verified, verbatim) ----------------
__global__ void __launch_bounds__(1024)
topk_kernel(const float* __restrict__ scoreF, int* __restrict__ gidx, float* __restrict__ gvals) {
    __shared__ unsigned long long buf[2][1024];
    const int b = blockIdx.x / NCLS;
    const int c = blockIdx.x % NCLS;
    const int t = threadIdx.x;

    if (c == 0 && t >= 512 && t < 512 + NQ) {
        int q  = t - 512;
        int gi = NSUP + q;
        int m  = NCLS * KK + q;
        gidx [b * MM + m] = gi;
        gvals[b * MM + m] = scoreF[(size_t)b * NN + gi];
    }

    const float* sc = scoreF + (size_t)b * NN + c * SS;
    unsigned long long v = 0ull;    // pad sinks
    if (t < SS)
        v = ((unsigned long long)__float_as_uint(sc[t]) << 32) | (unsigned int)(1023 - t);

    int p = 0;
    for (int k = 2; k <= 1024; k <<= 1) {
        for (int j = k >> 1; j > 0; j >>= 1) {
            unsigned long long o;
            if (j >= 64) {
                buf[p][t] = v;
                __syncthreads();
                o = buf[p][t ^ j];
                p ^= 1;   // next reuse of this buffer is 2 stages (1 barrier) away
            } else {
                unsigned int lo = __shfl_xor((unsigned int)(v & 0xFFFFFFFFu), j);
                unsigned int hi = __shfl_xor((unsigned int)(v >> 32), j);
                o = ((unsigned long long)hi << 32) | lo;
            }
            bool keepMax = (((t & k) == 0) == ((t & j) == 0));
            v = keepMax ? (v > o ? v : o) : (v < o ? v : o);
        }
    }

    if (t < KK) {
        int li = 1023 - (int)(v & 0xFFFFFFFFull);
        gidx [b * MM + c * KK + t] = c * SS + li;
        gvals[b * MM + c * KK + t] = __uint_as_float((unsigned int)(v >> 32));
    }
}

// ---------------- fused new_A + new_X + idx: LDS row staging, gather idx from L2 ----------------
// Single change vs R8-verified newxa: cidx LDS array removed — gather indices read
// directly from global gidx as int4 (L2-hot, 8.4KB/b, shared by 2096 blocks).
// LDS 24.4->16KB => 8 blocks/CU (wave cap), smaller tail, no lgkm dep at barrier.
__global__ void __launch_bounds__(256, 8)
newxa_kernel(const float* __restrict__ A, const float* __restrict__ X,
             const int* __restrict__ gidx, const float* __restrict__ gvals,
             float* __restrict__ outA, float* __restrict__ outX, float* __restrict__ outIdx) {
    __shared__ float rowA[NN];
    const int bm = blockIdx.x;            // b*MM + i
    const int b  = bm / MM;
    const int ri = gidx[bm];              // broadcast scalar load (L2-hot)

    // async stage of the 16KB A row: 4 global_load_lds_dwordx4 per wave,
    // wave-uniform LDS base + lane*16 (linear dest), streaming HBM order.
    {
        const float* arow = A + ((size_t)b * NN + ri) * NN;
        const int wv = threadIdx.x >> 6, ln = threadIdx.x & 63;
        #pragma unroll
        for (int sgm = 0; sgm < 4; ++sgm) {
            int base = (wv * 4 + sgm) * 256;               // float offset, wave-uniform
            const float* gsrc = arow + base + ln * 4;      // per-lane global addr
            float*       ldst = rowA + base;               // wave-uniform LDS base
            __builtin_amdgcn_global_load_lds(
                (__attribute__((address_space(1))) void*)(const_cast<float*>(gsrc)),
                (__attribute__((address_space(3))) void*)(ldst),
                16, 0, 0);
        }
    }

    // newX + idx overlap the staging latency
    if (threadIdx.x < DD) {
        float vscale = gvals[bm];
        outX[(size_t)bm * DD + threadIdx.x] =
            X[((size_t)b * NN + ri) * DD + threadIdx.x] * vscale;
        if (threadIdx.x == 0) outIdx[bm] = (float)ri;
    }
    __syncthreads();   // drains vmcnt (global_load_lds)

    // gather: indices via int4 from L2, values from LDS, coalesced f4 stores
    const int* gb = gidx + b * MM;        // 16B-aligned (b*8384 bytes)
    float* orow = outA + (size_t)bm * MM;
    for (int jj = threadIdx.x * 4; jj < MM; jj += 1024) {
        i4 c4 = *(const i4*)(gb + jj);
        f4 vv;
        vv.x = rowA[c4.x];
        vv.y = rowA[c4.y];
        vv.z = rowA[c4.z];
        vv.w = rowA[c4.w];
        *(f4*)(orow + jj) = vv;
    }
}

extern "C" void kernel_launch(void* const* d_in, const int* in_sizes, int n_in,
                              void* d_out, int out_size, void* d_ws, size_t ws_size,
                              hipStream_t stream) {
    const float* A  = (const float*)d_in[0];
    const float* X  = (const float*)d_in[1];
    const float* W  = (const float*)d_in[2];
    const float* bi = (const float*)d_in[3];

    float* outA   = (float*)d_out;                         // B*M*M
    float* outX   = outA + (size_t)BB * MM * MM;           // B*M*D
    float* outIdx = outX + (size_t)BB * MM * DD;           // B*M

    char* ws = (char*)d_ws;
    float* scoreF = (float*)ws;                                 // B*N*4 = 65536
    int*   gidx   = (int*)  (ws + 65536);                       // B*M*4 = 33536
    float* gvals  = (float*)(ws + 65536 + 33536);               // B*M*4 = 33536

    score_kernel<<<(BB * NN) / 4, 256, 0, stream>>>(X, W, bi, scoreF);
    topk_kernel<<<BB * NCLS, 1024, 0, stream>>>(scoreF, gidx, gvals);
    newxa_kernel<<<BB * MM, 256, 0, stream>>>(A, X, gidx, gvals, outA, outX, outIdx);
}